// Round 2
// baseline (1540.160 us; speedup 1.0000x reference)
//
#include <hip/hip_runtime.h>
#include <hip/hip_bf16.h>

// RNN scan, T=2048 B=64 D=128 H=256 C=5.
// Kernel 1 (xp_kernel): x_proj = inputs@W_ih^T + b_ih + b_hh via bf16 MFMA 16x16x32,
//   stored bf16 in d_ws.
// Kernel 2 (scan_kernel): 64 WGs (one per batch) x 512 threads. W_hh pinned in
//   registers (thread = 4 rows x 32 cols = 128 VGPR; asm-pinned + launch_bounds(512,2)
//   so the allocator has a 256-VGPR budget -> no remat/reload from L2, which was the
//   R0 bottleneck: 30 TB/s of W_hh re-reads). h double-buffered in padded LDS
//   (1 barrier/step). 8-lane DPP reduction. fp32 recurrence; xp read bf16, prefetched.

#define T_DIM 2048
#define B_DIM 64
#define D_DIM 128
#define H_DIM 256
#define C_DIM 5

typedef __attribute__((ext_vector_type(4))) float  floatx4;
typedef __attribute__((ext_vector_type(8))) short  shortx8;

__device__ __forceinline__ short f2bf(float f) {
  unsigned int u = __float_as_uint(f);
  unsigned int r = (u + 0x7FFFu + ((u >> 16) & 1u)) >> 16;  // RNE
  return (short)r;
}

template<int CTRL>
__device__ __forceinline__ float dpp_add(float x) {
  union { float f; int i; } u, v;
  u.f = x;
  v.i = __builtin_amdgcn_update_dpp(0, u.i, CTRL, 0xF, 0xF, true);
  return u.f + v.f;
}

// ---------------- x_proj kernel ----------------
__global__ __launch_bounds__(256) void xp_kernel(
    const float* __restrict__ x,       // (cnt*B, D) chunk base
    const float* __restrict__ W_ih,    // (H, D) row-major
    const float* __restrict__ b_ih,
    const float* __restrict__ b_hh,
    __hip_bfloat16* __restrict__ xp)   // (cnt*B, H) bf16
{
  // W_ih staged in LDS in MFMA-fragment order: [(nt*4+kf)*64 + lane] * 16B
  __shared__ __align__(16) short wlds[32768];  // 64 KB
  const int tid = threadIdx.x;
  {
    const int group = tid >> 2;        // 0..63 == nt*4+kf
    const int nt = group >> 2, kf = group & 3;
    const int sub = tid & 3;           // quad of the consuming lane
    const int k0 = kf * 32 + sub * 8;
    #pragma unroll
    for (int i = 0; i < 16; ++i) {
      const int n = nt * 16 + i;
      const float* src = W_ih + n * D_DIM + k0;
      float4 p0 = *(const float4*)(src);
      float4 p1 = *(const float4*)(src + 4);
      shortx8 v;
      v[0]=f2bf(p0.x); v[1]=f2bf(p0.y); v[2]=f2bf(p0.z); v[3]=f2bf(p0.w);
      v[4]=f2bf(p1.x); v[5]=f2bf(p1.y); v[6]=f2bf(p1.z); v[7]=f2bf(p1.w);
      *(shortx8*)&wlds[(group * 64 + sub * 16 + i) * 8] = v;
    }
  }
  __syncthreads();

  const int wv   = tid >> 6;           // wave 0..3 -> m-subtile
  const int lane = tid & 63;
  const int col  = lane & 15;
  const int quad = lane >> 4;
  const long m0  = (long)blockIdx.x * 64 + wv * 16;

  // A fragments: A[m = lane&15][k = quad*8 + j], 4 k-frags covering K=128
  shortx8 af[4];
  const float* arow = x + (m0 + col) * D_DIM + quad * 8;
  #pragma unroll
  for (int kf = 0; kf < 4; ++kf) {
    float4 p0 = *(const float4*)(arow + kf * 32);
    float4 p1 = *(const float4*)(arow + kf * 32 + 4);
    shortx8 v;
    v[0]=f2bf(p0.x); v[1]=f2bf(p0.y); v[2]=f2bf(p0.z); v[3]=f2bf(p0.w);
    v[4]=f2bf(p1.x); v[5]=f2bf(p1.y); v[6]=f2bf(p1.z); v[7]=f2bf(p1.w);
    af[kf] = v;
  }

  #pragma unroll
  for (int nt = 0; nt < 16; ++nt) {
    floatx4 acc = {0.f, 0.f, 0.f, 0.f};
    #pragma unroll
    for (int kf = 0; kf < 4; ++kf) {
      shortx8 bfrag = *(const shortx8*)&wlds[((nt * 4 + kf) * 64 + lane) * 8];
      acc = __builtin_amdgcn_mfma_f32_16x16x32_bf16(af[kf], bfrag, acc, 0, 0, 0);
    }
    const int n = nt * 16 + col;
    const float bias = b_ih[n] + b_hh[n];
    #pragma unroll
    for (int r = 0; r < 4; ++r) {
      const long m = m0 + quad * 4 + r;   // C: col=lane&15, row=quad*4+r
      xp[m * H_DIM + n] = __float2bfloat16(acc[r] + bias);
    }
  }
}

// ---------------- recurrent scan kernel ----------------
// pad: LDS index for h[j] is j + (j>>5)*4  (16B pad per 32 floats)
__global__ __launch_bounds__(512, 2) void scan_kernel(
    const __hip_bfloat16* __restrict__ xp,  // (cnt, B, H)
    const float* __restrict__ W_hh,         // (H, H)
    const float* __restrict__ W_fc,         // (C, H)
    const float* __restrict__ b_fc,         // (C)
    float* __restrict__ h_state,            // (B, H) carry between chunks
    float* __restrict__ out,                // (B, C)
    int cnt, int first, int last)
{
  __shared__ __align__(16) float hbuf[2][288];
  __shared__ float scratch[192];
  const int b   = blockIdx.x;
  const int tid = threadIdx.x;
  const int g   = tid >> 3;   // row group: rows 4g..4g+3
  const int c   = tid & 7;    // col chunk: cols 32c..32c+31

  // W_hh tile -> registers (4 rows x 8 float4 = 128 VGPRs), asm-pinned so the
  // compiler cannot rematerialize the loads inside the step loop (R0 lesson:
  // remat turned this into an L2-bandwidth-bound kernel).
  float4 w[4][8];
  const float* wbase = W_hh + (g * 4) * H_DIM + c * 32;
  #pragma unroll
  for (int r = 0; r < 4; ++r)
    #pragma unroll
    for (int q = 0; q < 8; ++q) {
      w[r][q] = *(const float4*)(wbase + r * H_DIM + q * 4);
      asm volatile("" : "+v"(w[r][q].x), "+v"(w[r][q].y),
                        "+v"(w[r][q].z), "+v"(w[r][q].w));
    }

  const int row_w = g * 4 + (c & 3);
  const int widx  = row_w + (row_w >> 5) * 4;
  if (c < 4)
    hbuf[0][widx] = first ? 0.f : h_state[b * H_DIM + row_w];
  __syncthreads();

  const __hip_bfloat16* xpp = xp + (size_t)b * H_DIM + row_w;
  __hip_bfloat16 xcur = xpp[0];
  int cur = 0;
  float hnlast = 0.f;

  for (int s = 0; s < cnt; ++s) {
    // prefetch next step's xp (raw bf16; converted only at use next iter)
    __hip_bfloat16 xnext = xpp[(size_t)(s + 1 < cnt ? s + 1 : s) * (B_DIM * H_DIM)];

    const float* hb = hbuf[cur];
    float4 hv[8];
    #pragma unroll
    for (int q = 0; q < 8; ++q)
      hv[q] = *(const float4*)(hb + c * 36 + q * 4);

    float a0 = 0.f, a1 = 0.f, a2 = 0.f, a3 = 0.f;
    #pragma unroll
    for (int q = 0; q < 8; ++q) {
      a0 = fmaf(w[0][q].x, hv[q].x, a0); a0 = fmaf(w[0][q].y, hv[q].y, a0);
      a0 = fmaf(w[0][q].z, hv[q].z, a0); a0 = fmaf(w[0][q].w, hv[q].w, a0);
      a1 = fmaf(w[1][q].x, hv[q].x, a1); a1 = fmaf(w[1][q].y, hv[q].y, a1);
      a1 = fmaf(w[1][q].z, hv[q].z, a1); a1 = fmaf(w[1][q].w, hv[q].w, a1);
      a2 = fmaf(w[2][q].x, hv[q].x, a2); a2 = fmaf(w[2][q].y, hv[q].y, a2);
      a2 = fmaf(w[2][q].z, hv[q].z, a2); a2 = fmaf(w[2][q].w, hv[q].w, a2);
      a3 = fmaf(w[3][q].x, hv[q].x, a3); a3 = fmaf(w[3][q].y, hv[q].y, a3);
      a3 = fmaf(w[3][q].z, hv[q].z, a3); a3 = fmaf(w[3][q].w, hv[q].w, a3);
    }
    // reduce across the 8 column-lanes: half_mirror, quad mirror, quad swap
    a0 = dpp_add<0x141>(a0); a0 = dpp_add<0x1B>(a0); a0 = dpp_add<0xB1>(a0);
    a1 = dpp_add<0x141>(a1); a1 = dpp_add<0x1B>(a1); a1 = dpp_add<0xB1>(a1);
    a2 = dpp_add<0x141>(a2); a2 = dpp_add<0x1B>(a2); a2 = dpp_add<0xB1>(a2);
    a3 = dpp_add<0x141>(a3); a3 = dpp_add<0x1B>(a3); a3 = dpp_add<0xB1>(a3);

    float v01 = (c & 1) ? a1 : a0;
    float v23 = (c & 1) ? a3 : a2;
    float v   = (c & 2) ? v23 : v01;

    float p = v + (float)xcur;
    xcur = xnext;
    // tanh(p) = 1 - 2/(e^{2p}+1); saturates correctly at +/-inf
    float e  = __expf(2.f * p);
    float hn = 1.f - __fdividef(2.f, e + 1.f);
    hnlast = hn;
    if (c < 4) hbuf[cur ^ 1][widx] = hn;
    __syncthreads();
    cur ^= 1;
  }

  if (c < 4) h_state[b * H_DIM + row_w] = hnlast;

  if (last) {
    const float* hb = hbuf[cur];
    if (tid < 160) {                       // 5 classes x 32 partials
      const int c5 = tid >> 5, i = tid & 31;
      float pp = 0.f;
      #pragma unroll
      for (int jj = 0; jj < 8; ++jj) {
        const int j = i * 8 + jj;
        pp += W_fc[c5 * H_DIM + j] * hb[j + (j >> 5) * 4];
      }
      scratch[tid] = pp;
    }
    __syncthreads();
    if (tid < C_DIM) {
      float l = b_fc[tid];
      for (int i = 0; i < 32; ++i) l += scratch[tid * 32 + i];
      scratch[160 + tid] = l;
    }
    __syncthreads();
    if (tid == 0) {
      float mx = scratch[160];
      for (int i = 1; i < C_DIM; ++i) mx = fmaxf(mx, scratch[160 + i]);
      float se = 0.f;
      for (int i = 0; i < C_DIM; ++i) se += __expf(scratch[160 + i] - mx);
      const float lse = mx + __logf(se);
      for (int i = 0; i < C_DIM; ++i) out[b * C_DIM + i] = scratch[160 + i] - lse;
    }
  }
}

extern "C" void kernel_launch(void* const* d_in, const int* in_sizes, int n_in,
                              void* d_out, int out_size, void* d_ws, size_t ws_size,
                              hipStream_t stream) {
  (void)in_sizes; (void)n_in; (void)out_size;
  const float* x    = (const float*)d_in[0];
  const float* W_ih = (const float*)d_in[1];
  const float* W_hh = (const float*)d_in[2];
  const float* b_ih = (const float*)d_in[3];
  const float* b_hh = (const float*)d_in[4];
  const float* W_fc = (const float*)d_in[5];
  const float* b_fc = (const float*)d_in[6];
  float* out = (float*)d_out;

  char* ws = (char*)d_ws;
  float* h_state = (float*)ws;                              // 64 KB
  __hip_bfloat16* xp = (__hip_bfloat16*)(ws + 65536);
  const size_t avail = ws_size > 65536 ? ws_size - 65536 : 0;
  long Tc = (long)(avail / ((size_t)B_DIM * H_DIM * 2));    // timesteps per chunk
  if (Tc > T_DIM) Tc = T_DIM;
  if (Tc < 1) Tc = 1;

  for (long t0 = 0; t0 < T_DIM; t0 += Tc) {
    const long cnt = (T_DIM - t0 < Tc) ? (T_DIM - t0) : Tc;
    xp_kernel<<<dim3((unsigned)cnt), dim3(256), 0, stream>>>(
        x + t0 * B_DIM * D_DIM, W_ih, b_ih, b_hh, xp);
    scan_kernel<<<dim3(B_DIM), dim3(512), 0, stream>>>(
        xp, W_hh, W_fc, b_fc, h_state, out,
        (int)cnt, t0 == 0 ? 1 : 0, (t0 + cnt == T_DIM) ? 1 : 0);
  }
}

// Round 3
// 1224.358 us; speedup vs baseline: 1.2579x; 1.2579x over previous
//
#include <hip/hip_runtime.h>

// RNN scan, T=2048 B=64 D=128 H=256 C=5.
// Kernel 1 (xp_kernel): x_proj = inputs@W_ih^T + b_ih + b_hh via bf16 MFMA 16x16x32,
//   stored fp16 in d_ws. 8 timesteps per block (W_ih LDS staging amortized).
// Kernel 2 (scan_kernel): 64 WGs (one per batch) x 512 threads. W_hh in fp16 packed
//   half2 registers (64 VGPR/thread; whole-reg asm pins + in-loop memory clobber to
//   forbid remat — R1/R2 showed the compiler otherwise reloads W from L2 every step,
//   30 TB/s = L2-bound). Inner product via v_dot2_f32_f16 (2 MAC/instr).
//   h double-buffered in padded fp16 LDS (conflict-free ds_read_b128), 1 barrier/step.
//   8-lane DPP butterfly reduction. fp32 accumulate + tanh.

#define T_DIM 2048
#define B_DIM 64
#define D_DIM 128
#define H_DIM 256
#define C_DIM 5

using floatx4 = __attribute__((ext_vector_type(4))) float;
using shortx8 = __attribute__((ext_vector_type(8))) short;
using half2v  = __attribute__((ext_vector_type(2))) _Float16;
using half8v  = __attribute__((ext_vector_type(8))) _Float16;

__device__ __forceinline__ short f2bf(float f) {
  unsigned int u = __float_as_uint(f);
  unsigned int r = (u + 0x7FFFu + ((u >> 16) & 1u)) >> 16;  // RNE
  return (short)r;
}

__device__ __forceinline__ float fdot2(half2v a, half2v b, float c) {
#if __has_builtin(__builtin_amdgcn_fdot2)
  return __builtin_amdgcn_fdot2(a, b, c, false);
#else
  return fmaf((float)a[1], (float)b[1], fmaf((float)a[0], (float)b[0], c));
#endif
}

template<int CTRL>
__device__ __forceinline__ float dpp_add(float x) {
  union { float f; int i; } u, v;
  u.f = x;
  v.i = __builtin_amdgcn_update_dpp(0, u.i, CTRL, 0xF, 0xF, true);
  return u.f + v.f;
}

// ---------------- x_proj kernel ----------------
#define TS_PER_BLOCK 8
__global__ __launch_bounds__(256) void xp_kernel(
    const float* __restrict__ x,       // (cnt*B, D) chunk base
    const float* __restrict__ W_ih,    // (H, D) row-major
    const float* __restrict__ b_ih,
    const float* __restrict__ b_hh,
    _Float16* __restrict__ xp,         // (cnt*B, H) fp16
    int cnt)
{
  // W_ih staged in LDS in MFMA-fragment order: [(nt*4+kf)*64 + lane] * 16B
  __shared__ __align__(16) short wlds[32768];  // 64 KB
  const int tid = threadIdx.x;
  {
    const int group = tid >> 2;        // 0..63 == nt*4+kf
    const int sub = tid & 3;           // quad of the consuming lane
    const int kf = group & 3;
    const int k0 = kf * 32 + sub * 8;
    #pragma unroll
    for (int i = 0; i < 16; ++i) {
      const int n = (group >> 2) * 16 + i;
      const float* src = W_ih + n * D_DIM + k0;
      float4 p0 = *(const float4*)(src);
      float4 p1 = *(const float4*)(src + 4);
      shortx8 v;
      v[0]=f2bf(p0.x); v[1]=f2bf(p0.y); v[2]=f2bf(p0.z); v[3]=f2bf(p0.w);
      v[4]=f2bf(p1.x); v[5]=f2bf(p1.y); v[6]=f2bf(p1.z); v[7]=f2bf(p1.w);
      *(shortx8*)&wlds[(group * 64 + sub * 16 + i) * 8] = v;
    }
  }
  __syncthreads();

  const int wv   = tid >> 6;           // wave 0..3 -> m-subtile
  const int lane = tid & 63;
  const int col  = lane & 15;
  const int quad = lane >> 4;

  float bias[16];
  #pragma unroll
  for (int nt = 0; nt < 16; ++nt)
    bias[nt] = b_ih[nt * 16 + col] + b_hh[nt * 16 + col];

  for (int tl = 0; tl < TS_PER_BLOCK; ++tl) {
    const int t = blockIdx.x * TS_PER_BLOCK + tl;
    if (t >= cnt) break;
    const long m0 = (long)t * 64 + wv * 16;

    // A fragments: A[m = lane&15][k = quad*8 + j], 4 k-frags covering K=128
    shortx8 af[4];
    const float* arow = x + (m0 + col) * D_DIM + quad * 8;
    #pragma unroll
    for (int kf = 0; kf < 4; ++kf) {
      float4 p0 = *(const float4*)(arow + kf * 32);
      float4 p1 = *(const float4*)(arow + kf * 32 + 4);
      shortx8 v;
      v[0]=f2bf(p0.x); v[1]=f2bf(p0.y); v[2]=f2bf(p0.z); v[3]=f2bf(p0.w);
      v[4]=f2bf(p1.x); v[5]=f2bf(p1.y); v[6]=f2bf(p1.z); v[7]=f2bf(p1.w);
      af[kf] = v;
    }

    #pragma unroll
    for (int nt = 0; nt < 16; ++nt) {
      floatx4 acc = {0.f, 0.f, 0.f, 0.f};
      #pragma unroll
      for (int kf = 0; kf < 4; ++kf) {
        shortx8 bfrag = *(const shortx8*)&wlds[((nt * 4 + kf) * 64 + lane) * 8];
        acc = __builtin_amdgcn_mfma_f32_16x16x32_bf16(af[kf], bfrag, acc, 0, 0, 0);
      }
      const int n = nt * 16 + col;
      #pragma unroll
      for (int r = 0; r < 4; ++r) {
        const long m = m0 + quad * 4 + r;   // C: col=lane&15, row=quad*4+r
        xp[m * H_DIM + n] = (_Float16)(acc[r] + bias[nt]);
      }
    }
  }
}

// ---------------- recurrent scan kernel ----------------
// h LDS layout (fp16): h[j] at half-index (j>>5)*40 + (j&31)  — 64B data + 16B pad
// per 32-element group -> the 8 broadcast segments of each ds_read_b128 hit the 8
// distinct 4-bank groups (banks = (20c+4q) mod 32, all distinct over c).
__global__ __launch_bounds__(512, 2) void scan_kernel(
    const _Float16* __restrict__ xp,   // (cnt, B, H)
    const float* __restrict__ W_hh,    // (H, H)
    const float* __restrict__ W_fc,    // (C, H)
    const float* __restrict__ b_fc,    // (C)
    float* __restrict__ h_state,       // (B, H) carry between chunks
    float* __restrict__ out,           // (B, C)
    int cnt, int first, int last)
{
  __shared__ __align__(16) _Float16 hbuf[2][320];
  __shared__ float scratch[192];
  const int b   = blockIdx.x;
  const int tid = threadIdx.x;
  const int g   = tid >> 3;   // row group: rows 4g..4g+3
  const int c   = tid & 7;    // col chunk: cols 32c..32c+31

  // W_hh tile -> fp16 packed registers (4 rows x 16 half2 = 64 VGPRs)
  half2v w[4][16];
  const float* wbase = W_hh + (g * 4) * H_DIM + c * 32;
  #pragma unroll
  for (int r = 0; r < 4; ++r)
    #pragma unroll
    for (int i = 0; i < 8; ++i) {
      float4 f = *(const float4*)(wbase + r * H_DIM + i * 4);
      half2v lo, hi;
      lo[0] = (_Float16)f.x; lo[1] = (_Float16)f.y;
      hi[0] = (_Float16)f.z; hi[1] = (_Float16)f.w;
      w[r][2 * i]     = lo;
      w[r][2 * i + 1] = hi;
    }
  // whole-register pins: each half2 is one VGPR; the value becomes asm output,
  // which LLVM will not rematerialize.
  #pragma unroll
  for (int r = 0; r < 4; ++r)
    #pragma unroll
    for (int i = 0; i < 16; ++i)
      asm volatile("" : "+v"(w[r][i]));

  const int row_w = g * 4 + (c & 3);
  const int widx  = (row_w >> 5) * 40 + (row_w & 31);
  if (c < 4)
    hbuf[0][widx] = (_Float16)(first ? 0.f : h_state[b * H_DIM + row_w]);
  __syncthreads();

  const _Float16* xpp = xp + (size_t)b * H_DIM + row_w;
  _Float16 xcur = xpp[0];
  int cur = 0;
  float hnlast = 0.f;

  for (int s = 0; s < cnt; ++s) {
    // forbid rematerializing the W loads into the loop: after this clobber a
    // reload would be reading potentially-different memory.
    asm volatile("" ::: "memory");
    // prefetch next step's xp
    _Float16 xnext = xpp[(size_t)(s + 1 < cnt ? s + 1 : s) * (B_DIM * H_DIM)];

    const _Float16* hb = hbuf[cur];
    float a0 = 0.f, a1 = 0.f, a2 = 0.f, a3 = 0.f;
    #pragma unroll
    for (int q = 0; q < 4; ++q) {
      half8v H = *(const half8v*)(hb + c * 40 + q * 8);
      const half2v* hp = (const half2v*)&H;
      #pragma unroll
      for (int i = 0; i < 4; ++i) {
        a0 = fdot2(w[0][q * 4 + i], hp[i], a0);
        a1 = fdot2(w[1][q * 4 + i], hp[i], a1);
        a2 = fdot2(w[2][q * 4 + i], hp[i], a2);
        a3 = fdot2(w[3][q * 4 + i], hp[i], a3);
      }
    }
    // reduce across the 8 column-lanes: butterfly xor {7,3,1}
    a0 = dpp_add<0x141>(a0); a0 = dpp_add<0x1B>(a0); a0 = dpp_add<0xB1>(a0);
    a1 = dpp_add<0x141>(a1); a1 = dpp_add<0x1B>(a1); a1 = dpp_add<0xB1>(a1);
    a2 = dpp_add<0x141>(a2); a2 = dpp_add<0x1B>(a2); a2 = dpp_add<0xB1>(a2);
    a3 = dpp_add<0x141>(a3); a3 = dpp_add<0x1B>(a3); a3 = dpp_add<0xB1>(a3);

    float v01 = (c & 1) ? a1 : a0;
    float v23 = (c & 1) ? a3 : a2;
    float v   = (c & 2) ? v23 : v01;

    float p = v + (float)xcur;
    xcur = xnext;
    // tanh(p) = 1 - 2/(e^{2p}+1); saturates correctly at +/-inf
    float e  = __expf(2.f * p);
    float hn = 1.f - __fdividef(2.f, e + 1.f);
    hnlast = hn;
    if (c < 4) hbuf[cur ^ 1][widx] = (_Float16)hn;
    __syncthreads();
    cur ^= 1;
  }

  if (c < 4) h_state[b * H_DIM + row_w] = hnlast;

  if (last) {
    const _Float16* hb = hbuf[cur];
    if (tid < 160) {                       // 5 classes x 32 partials
      const int c5 = tid >> 5, i = tid & 31;
      float pp = 0.f;
      #pragma unroll
      for (int jj = 0; jj < 8; ++jj) {
        const int j = i * 8 + jj;
        pp += W_fc[c5 * H_DIM + j] * (float)hb[(j >> 5) * 40 + (j & 31)];
      }
      scratch[tid] = pp;
    }
    __syncthreads();
    if (tid < C_DIM) {
      float l = b_fc[tid];
      for (int i = 0; i < 32; ++i) l += scratch[tid * 32 + i];
      scratch[160 + tid] = l;
    }
    __syncthreads();
    if (tid == 0) {
      float mx = scratch[160];
      for (int i = 1; i < C_DIM; ++i) mx = fmaxf(mx, scratch[160 + i]);
      float se = 0.f;
      for (int i = 0; i < C_DIM; ++i) se += __expf(scratch[160 + i] - mx);
      const float lse = mx + __logf(se);
      for (int i = 0; i < C_DIM; ++i) out[b * C_DIM + i] = scratch[160 + i] - lse;
    }
  }
}

extern "C" void kernel_launch(void* const* d_in, const int* in_sizes, int n_in,
                              void* d_out, int out_size, void* d_ws, size_t ws_size,
                              hipStream_t stream) {
  (void)in_sizes; (void)n_in; (void)out_size;
  const float* x    = (const float*)d_in[0];
  const float* W_ih = (const float*)d_in[1];
  const float* W_hh = (const float*)d_in[2];
  const float* b_ih = (const float*)d_in[3];
  const float* b_hh = (const float*)d_in[4];
  const float* W_fc = (const float*)d_in[5];
  const float* b_fc = (const float*)d_in[6];
  float* out = (float*)d_out;

  char* ws = (char*)d_ws;
  float* h_state = (float*)ws;                              // 64 KB
  _Float16* xp = (_Float16*)(ws + 65536);
  const size_t avail = ws_size > 65536 ? ws_size - 65536 : 0;
  long Tc = (long)(avail / ((size_t)B_DIM * H_DIM * sizeof(_Float16)));
  if (Tc > T_DIM) Tc = T_DIM;
  if (Tc < 1) Tc = 1;

  for (long t0 = 0; t0 < T_DIM; t0 += Tc) {
    const long cnt = (T_DIM - t0 < Tc) ? (T_DIM - t0) : Tc;
    const unsigned xpb = (unsigned)((cnt + TS_PER_BLOCK - 1) / TS_PER_BLOCK);
    xp_kernel<<<dim3(xpb), dim3(256), 0, stream>>>(
        x + t0 * B_DIM * D_DIM, W_ih, b_ih, b_hh, xp, (int)cnt);
    scan_kernel<<<dim3(B_DIM), dim3(512), 0, stream>>>(
        xp, W_hh, W_fc, b_fc, h_state, out,
        (int)cnt, t0 == 0 ? 1 : 0, (t0 + cnt == T_DIM) ? 1 : 0);
  }
}

// Round 5
// 1121.226 us; speedup vs baseline: 1.3736x; 1.0920x over previous
//
#include <hip/hip_runtime.h>

// RNN scan, T=2048 B=64 D=128 H=256 C=5.
// Kernel 1 (xp_kernel): x_proj = inputs@W_ih^T + b_ih + b_hh via bf16 MFMA 16x16x32,
//   stored fp16 in d_ws. 8 timesteps per block (W_ih LDS staging amortized).
// Kernel 2 (scan_kernel): 64 WGs (one per batch) x 512 threads. W_hh in fp16 packed
//   half2 registers (64 VGPR/thread). KEY FIX (R3 post-mortem): the AMDGPU RA spills
//   to chase occupancy — launch_bounds' 2nd arg only sets the waves/EU *floor*.
//   amdgpu_waves_per_eu(2,2) pins the ceiling too -> 256-VGPR budget -> no spill.
//   (R1: 84 regs/4-wave target; R3: 52 regs/8-wave target; both reloaded W every
//   step from L2/scratch at ~30 TB/s = the real bottleneck.)
//   Inner product via v_dot2_f32_f16 (2 MAC/instr). h double-buffered in padded fp16
//   LDS (conflict-free ds_read_b128), 1 barrier/step. 8-lane DPP butterfly reduction.
//   fp32 accumulate + tanh.

#define T_DIM 2048
#define B_DIM 64
#define D_DIM 128
#define H_DIM 256
#define C_DIM 5

using floatx4 = __attribute__((ext_vector_type(4))) float;
using shortx8 = __attribute__((ext_vector_type(8))) short;
using half2v  = __attribute__((ext_vector_type(2))) _Float16;
using half8v  = __attribute__((ext_vector_type(8))) _Float16;

__device__ __forceinline__ short f2bf(float f) {
  unsigned int u = __float_as_uint(f);
  unsigned int r = (u + 0x7FFFu + ((u >> 16) & 1u)) >> 16;  // RNE
  return (short)r;
}

__device__ __forceinline__ float fdot2(half2v a, half2v b, float c) {
#if __has_builtin(__builtin_amdgcn_fdot2)
  return __builtin_amdgcn_fdot2(a, b, c, false);
#else
  return fmaf((float)a[1], (float)b[1], fmaf((float)a[0], (float)b[0], c));
#endif
}

template<int CTRL>
__device__ __forceinline__ float dpp_add(float x) {
  union { float f; int i; } u, v;
  u.f = x;
  v.i = __builtin_amdgcn_update_dpp(0, u.i, CTRL, 0xF, 0xF, true);
  return u.f + v.f;
}

// ---------------- x_proj kernel ----------------
#define TS_PER_BLOCK 8
__global__ __launch_bounds__(256) void xp_kernel(
    const float* __restrict__ x,       // (cnt*B, D) chunk base
    const float* __restrict__ W_ih,    // (H, D) row-major
    const float* __restrict__ b_ih,
    const float* __restrict__ b_hh,
    _Float16* __restrict__ xp,         // (cnt*B, H) fp16
    int cnt)
{
  // W_ih staged in LDS in MFMA-fragment order: [(nt*4+kf)*64 + lane] * 16B
  __shared__ __align__(16) short wlds[32768];  // 64 KB
  const int tid = threadIdx.x;
  {
    const int group = tid >> 2;        // 0..63 == nt*4+kf
    const int sub = tid & 3;           // quad of the consuming lane
    const int kf = group & 3;
    const int k0 = kf * 32 + sub * 8;
    #pragma unroll
    for (int i = 0; i < 16; ++i) {
      const int n = (group >> 2) * 16 + i;
      const float* src = W_ih + n * D_DIM + k0;
      float4 p0 = *(const float4*)(src);
      float4 p1 = *(const float4*)(src + 4);
      shortx8 v;
      v[0]=f2bf(p0.x); v[1]=f2bf(p0.y); v[2]=f2bf(p0.z); v[3]=f2bf(p0.w);
      v[4]=f2bf(p1.x); v[5]=f2bf(p1.y); v[6]=f2bf(p1.z); v[7]=f2bf(p1.w);
      *(shortx8*)&wlds[(group * 64 + sub * 16 + i) * 8] = v;
    }
  }
  __syncthreads();

  const int wv   = tid >> 6;           // wave 0..3 -> m-subtile
  const int lane = tid & 63;
  const int col  = lane & 15;
  const int quad = lane >> 4;

  float bias[16];
  #pragma unroll
  for (int nt = 0; nt < 16; ++nt)
    bias[nt] = b_ih[nt * 16 + col] + b_hh[nt * 16 + col];

  for (int tl = 0; tl < TS_PER_BLOCK; ++tl) {
    const int t = blockIdx.x * TS_PER_BLOCK + tl;
    if (t >= cnt) break;
    const long m0 = (long)t * 64 + wv * 16;

    // A fragments: A[m = lane&15][k = quad*8 + j], 4 k-frags covering K=128
    shortx8 af[4];
    const float* arow = x + (m0 + col) * D_DIM + quad * 8;
    #pragma unroll
    for (int kf = 0; kf < 4; ++kf) {
      float4 p0 = *(const float4*)(arow + kf * 32);
      float4 p1 = *(const float4*)(arow + kf * 32 + 4);
      shortx8 v;
      v[0]=f2bf(p0.x); v[1]=f2bf(p0.y); v[2]=f2bf(p0.z); v[3]=f2bf(p0.w);
      v[4]=f2bf(p1.x); v[5]=f2bf(p1.y); v[6]=f2bf(p1.z); v[7]=f2bf(p1.w);
      af[kf] = v;
    }

    #pragma unroll
    for (int nt = 0; nt < 16; ++nt) {
      floatx4 acc = {0.f, 0.f, 0.f, 0.f};
      #pragma unroll
      for (int kf = 0; kf < 4; ++kf) {
        shortx8 bfrag = *(const shortx8*)&wlds[((nt * 4 + kf) * 64 + lane) * 8];
        acc = __builtin_amdgcn_mfma_f32_16x16x32_bf16(af[kf], bfrag, acc, 0, 0, 0);
      }
      const int n = nt * 16 + col;
      #pragma unroll
      for (int r = 0; r < 4; ++r) {
        const long m = m0 + quad * 4 + r;   // C: col=lane&15, row=quad*4+r
        xp[m * H_DIM + n] = (_Float16)(acc[r] + bias[nt]);
      }
    }
  }
}

// ---------------- recurrent scan kernel ----------------
// h LDS layout (fp16): h[j] at half-index (j>>5)*40 + (j&31)  — 64B data + 16B pad
// per 32-element group -> the 8 broadcast segments of each ds_read_b128 hit the 8
// distinct 4-bank groups (banks = (20c+4q) mod 32, all distinct over c).
__global__ __launch_bounds__(512)
__attribute__((amdgpu_waves_per_eu(2, 2)))   // cap occupancy chase: 256-VGPR budget
void scan_kernel(
    const _Float16* __restrict__ xp,   // (cnt, B, H)
    const float* __restrict__ W_hh,    // (H, H)
    const float* __restrict__ W_fc,    // (C, H)
    const float* __restrict__ b_fc,    // (C)
    float* __restrict__ h_state,       // (B, H) carry between chunks
    float* __restrict__ out,           // (B, C)
    int cnt, int first, int last)
{
  __shared__ __align__(16) _Float16 hbuf[2][320];
  __shared__ float scratch[192];
  const int b   = blockIdx.x;
  const int tid = threadIdx.x;
  const int g   = tid >> 3;   // row group: rows 4g..4g+3
  const int c   = tid & 7;    // col chunk: cols 32c..32c+31

  // W_hh tile -> fp16 packed registers (4 rows x 16 half2 = 64 VGPRs)
  half2v w[4][16];
  const float* wbase = W_hh + (g * 4) * H_DIM + c * 32;
  #pragma unroll
  for (int r = 0; r < 4; ++r)
    #pragma unroll
    for (int i = 0; i < 8; ++i) {
      float4 f = *(const float4*)(wbase + r * H_DIM + i * 4);
      half2v lo, hi;
      lo[0] = (_Float16)f.x; lo[1] = (_Float16)f.y;
      hi[0] = (_Float16)f.z; hi[1] = (_Float16)f.w;
      w[r][2 * i]     = lo;
      w[r][2 * i + 1] = hi;
    }
  // whole-register pins: each half2 is one VGPR; the value becomes asm output,
  // which LLVM will not rematerialize.
  #pragma unroll
  for (int r = 0; r < 4; ++r)
    #pragma unroll
    for (int i = 0; i < 16; ++i)
      asm volatile("" : "+v"(w[r][i]));

  const int row_w = g * 4 + (c & 3);
  const int widx  = (row_w >> 5) * 40 + (row_w & 31);
  if (c < 4)
    hbuf[0][widx] = (_Float16)(first ? 0.f : h_state[b * H_DIM + row_w]);
  __syncthreads();

  const _Float16* xpp = xp + (size_t)b * H_DIM + row_w;
  _Float16 xcur = xpp[0];
  int cur = 0;
  float hnlast = 0.f;

  for (int s = 0; s < cnt; ++s) {
    // prefetch next step's xp
    _Float16 xnext = xpp[(size_t)(s + 1 < cnt ? s + 1 : s) * (B_DIM * H_DIM)];

    const _Float16* hb = hbuf[cur];
    float a0 = 0.f, a1 = 0.f, a2 = 0.f, a3 = 0.f;
    #pragma unroll
    for (int q = 0; q < 4; ++q) {
      half8v H = *(const half8v*)(hb + c * 40 + q * 8);
      const half2v* hp = (const half2v*)&H;
      #pragma unroll
      for (int i = 0; i < 4; ++i) {
        a0 = fdot2(w[0][q * 4 + i], hp[i], a0);
        a1 = fdot2(w[1][q * 4 + i], hp[i], a1);
        a2 = fdot2(w[2][q * 4 + i], hp[i], a2);
        a3 = fdot2(w[3][q * 4 + i], hp[i], a3);
      }
    }
    // reduce across the 8 column-lanes: butterfly xor {7,3,1}
    a0 = dpp_add<0x141>(a0); a0 = dpp_add<0x1B>(a0); a0 = dpp_add<0xB1>(a0);
    a1 = dpp_add<0x141>(a1); a1 = dpp_add<0x1B>(a1); a1 = dpp_add<0xB1>(a1);
    a2 = dpp_add<0x141>(a2); a2 = dpp_add<0x1B>(a2); a2 = dpp_add<0xB1>(a2);
    a3 = dpp_add<0x141>(a3); a3 = dpp_add<0x1B>(a3); a3 = dpp_add<0xB1>(a3);

    float v01 = (c & 1) ? a1 : a0;
    float v23 = (c & 1) ? a3 : a2;
    float v   = (c & 2) ? v23 : v01;

    float p = v + (float)xcur;
    xcur = xnext;
    // tanh(p) = 1 - 2/(e^{2p}+1); saturates correctly at +/-inf
    float e  = __expf(2.f * p);
    float hn = 1.f - __fdividef(2.f, e + 1.f);
    hnlast = hn;
    if (c < 4) hbuf[cur ^ 1][widx] = (_Float16)hn;
    __syncthreads();
    cur ^= 1;
  }

  if (c < 4) h_state[b * H_DIM + row_w] = hnlast;

  if (last) {
    const _Float16* hb = hbuf[cur];
    if (tid < 160) {                       // 5 classes x 32 partials
      const int c5 = tid >> 5, i = tid & 31;
      float pp = 0.f;
      #pragma unroll
      for (int jj = 0; jj < 8; ++jj) {
        const int j = i * 8 + jj;
        pp += W_fc[c5 * H_DIM + j] * (float)hb[(j >> 5) * 40 + (j & 31)];
      }
      scratch[tid] = pp;
    }
    __syncthreads();
    if (tid < C_DIM) {
      float l = b_fc[tid];
      for (int i = 0; i < 32; ++i) l += scratch[tid * 32 + i];
      scratch[160 + tid] = l;
    }
    __syncthreads();
    if (tid == 0) {
      float mx = scratch[160];
      for (int i = 1; i < C_DIM; ++i) mx = fmaxf(mx, scratch[160 + i]);
      float se = 0.f;
      for (int i = 0; i < C_DIM; ++i) se += __expf(scratch[160 + i] - mx);
      const float lse = mx + __logf(se);
      for (int i = 0; i < C_DIM; ++i) out[b * C_DIM + i] = scratch[160 + i] - lse;
    }
  }
}

extern "C" void kernel_launch(void* const* d_in, const int* in_sizes, int n_in,
                              void* d_out, int out_size, void* d_ws, size_t ws_size,
                              hipStream_t stream) {
  (void)in_sizes; (void)n_in; (void)out_size;
  const float* x    = (const float*)d_in[0];
  const float* W_ih = (const float*)d_in[1];
  const float* W_hh = (const float*)d_in[2];
  const float* b_ih = (const float*)d_in[3];
  const float* b_hh = (const float*)d_in[4];
  const float* W_fc = (const float*)d_in[5];
  const float* b_fc = (const float*)d_in[6];
  float* out = (float*)d_out;

  char* ws = (char*)d_ws;
  float* h_state = (float*)ws;                              // 64 KB
  _Float16* xp = (_Float16*)(ws + 65536);
  const size_t avail = ws_size > 65536 ? ws_size - 65536 : 0;
  long Tc = (long)(avail / ((size_t)B_DIM * H_DIM * sizeof(_Float16)));
  if (Tc > T_DIM) Tc = T_DIM;
  if (Tc < 1) Tc = 1;

  for (long t0 = 0; t0 < T_DIM; t0 += Tc) {
    const long cnt = (T_DIM - t0 < Tc) ? (T_DIM - t0) : Tc;
    const unsigned xpb = (unsigned)((cnt + TS_PER_BLOCK - 1) / TS_PER_BLOCK);
    xp_kernel<<<dim3(xpb), dim3(256), 0, stream>>>(
        x + t0 * B_DIM * D_DIM, W_ih, b_ih, b_hh, xp, (int)cnt);
    scan_kernel<<<dim3(B_DIM), dim3(512), 0, stream>>>(
        xp, W_hh, W_fc, b_fc, h_state, out,
        (int)cnt, t0 == 0 ? 1 : 0, (t0 + cnt == T_DIM) ? 1 : 0);
  }
}

// Round 6
// 1120.192 us; speedup vs baseline: 1.3749x; 1.0009x over previous
//
#include <hip/hip_runtime.h>

// RNN scan, T=2048 B=64 D=128 H=256 C=5.
// Kernel 1 (xp_kernel): x_proj = inputs@W_ih^T + b_ih + b_hh via bf16 MFMA 16x16x32,
//   stored fp16 in d_ws. 8 timesteps per block (W_ih LDS staging amortized).
// Kernel 2 (scan_kernel): 64 WGs (one per batch) x 512 threads.
//   - W_hh resident in fp16 packed half2 registers (64 VGPR/thread); needs
//     amdgpu_waves_per_eu(2,2): the RA otherwise spills to chase 8-wave occupancy
//     (R1-R5: VGPR 84/76/52 -> 88 once capped). launch_bounds' 2nd arg is only a floor.
//   - KEY FIX (R5 post-mortem): __syncthreads forces s_waitcnt vmcnt(0) before
//     s_barrier, so the per-step global xp prefetch serialized a full L3/HBM miss
//     latency into every one of the 2048 steps (~800 of ~1190 cyc/step). Replace with
//     raw `s_waitcnt lgkmcnt(0); s_barrier` (LDS-only drain) + 2-step-deep xp
//     prefetch so the vmem latency is hidden across barriers.
//   - v_dot2_f32_f16 inner product, h double-buffered in padded fp16 LDS
//     (conflict-free ds_read_b128), 8-lane DPP butterfly reduce, fp32 tanh.

#define T_DIM 2048
#define B_DIM 64
#define D_DIM 128
#define H_DIM 256
#define C_DIM 5

using floatx4 = __attribute__((ext_vector_type(4))) float;
using shortx8 = __attribute__((ext_vector_type(8))) short;
using half2v  = __attribute__((ext_vector_type(2))) _Float16;
using half8v  = __attribute__((ext_vector_type(8))) _Float16;

__device__ __forceinline__ short f2bf(float f) {
  unsigned int u = __float_as_uint(f);
  unsigned int r = (u + 0x7FFFu + ((u >> 16) & 1u)) >> 16;  // RNE
  return (short)r;
}

__device__ __forceinline__ float fdot2(half2v a, half2v b, float c) {
#if __has_builtin(__builtin_amdgcn_fdot2)
  return __builtin_amdgcn_fdot2(a, b, c, false);
#else
  return fmaf((float)a[1], (float)b[1], fmaf((float)a[0], (float)b[0], c));
#endif
}

template<int CTRL>
__device__ __forceinline__ float dpp_add(float x) {
  union { float f; int i; } u, v;
  u.f = x;
  v.i = __builtin_amdgcn_update_dpp(0, u.i, CTRL, 0xF, 0xF, true);
  return u.f + v.f;
}

// Workgroup barrier that drains ONLY the LDS counter — global loads may remain
// in flight across it (unlike __syncthreads, which drains vmcnt(0) too).
__device__ __forceinline__ void barrier_lds_only() {
  asm volatile("s_waitcnt lgkmcnt(0)\n\ts_barrier" ::: "memory");
}

// ---------------- x_proj kernel ----------------
#define TS_PER_BLOCK 8
__global__ __launch_bounds__(256) void xp_kernel(
    const float* __restrict__ x,       // (cnt*B, D) chunk base
    const float* __restrict__ W_ih,    // (H, D) row-major
    const float* __restrict__ b_ih,
    const float* __restrict__ b_hh,
    _Float16* __restrict__ xp,         // (cnt*B, H) fp16
    int cnt)
{
  // W_ih staged in LDS in MFMA-fragment order: [(nt*4+kf)*64 + lane] * 16B
  __shared__ __align__(16) short wlds[32768];  // 64 KB
  const int tid = threadIdx.x;
  {
    const int group = tid >> 2;        // 0..63 == nt*4+kf
    const int sub = tid & 3;           // quad of the consuming lane
    const int kf = group & 3;
    const int k0 = kf * 32 + sub * 8;
    #pragma unroll
    for (int i = 0; i < 16; ++i) {
      const int n = (group >> 2) * 16 + i;
      const float* src = W_ih + n * D_DIM + k0;
      float4 p0 = *(const float4*)(src);
      float4 p1 = *(const float4*)(src + 4);
      shortx8 v;
      v[0]=f2bf(p0.x); v[1]=f2bf(p0.y); v[2]=f2bf(p0.z); v[3]=f2bf(p0.w);
      v[4]=f2bf(p1.x); v[5]=f2bf(p1.y); v[6]=f2bf(p1.z); v[7]=f2bf(p1.w);
      *(shortx8*)&wlds[(group * 64 + sub * 16 + i) * 8] = v;
    }
  }
  __syncthreads();

  const int wv   = tid >> 6;           // wave 0..3 -> m-subtile
  const int lane = tid & 63;
  const int col  = lane & 15;
  const int quad = lane >> 4;

  float bias[16];
  #pragma unroll
  for (int nt = 0; nt < 16; ++nt)
    bias[nt] = b_ih[nt * 16 + col] + b_hh[nt * 16 + col];

  for (int tl = 0; tl < TS_PER_BLOCK; ++tl) {
    const int t = blockIdx.x * TS_PER_BLOCK + tl;
    if (t >= cnt) break;
    const long m0 = (long)t * 64 + wv * 16;

    // A fragments: A[m = lane&15][k = quad*8 + j], 4 k-frags covering K=128
    shortx8 af[4];
    const float* arow = x + (m0 + col) * D_DIM + quad * 8;
    #pragma unroll
    for (int kf = 0; kf < 4; ++kf) {
      float4 p0 = *(const float4*)(arow + kf * 32);
      float4 p1 = *(const float4*)(arow + kf * 32 + 4);
      shortx8 v;
      v[0]=f2bf(p0.x); v[1]=f2bf(p0.y); v[2]=f2bf(p0.z); v[3]=f2bf(p0.w);
      v[4]=f2bf(p1.x); v[5]=f2bf(p1.y); v[6]=f2bf(p1.z); v[7]=f2bf(p1.w);
      af[kf] = v;
    }

    #pragma unroll
    for (int nt = 0; nt < 16; ++nt) {
      floatx4 acc = {0.f, 0.f, 0.f, 0.f};
      #pragma unroll
      for (int kf = 0; kf < 4; ++kf) {
        shortx8 bfrag = *(const shortx8*)&wlds[((nt * 4 + kf) * 64 + lane) * 8];
        acc = __builtin_amdgcn_mfma_f32_16x16x32_bf16(af[kf], bfrag, acc, 0, 0, 0);
      }
      const int n = nt * 16 + col;
      #pragma unroll
      for (int r = 0; r < 4; ++r) {
        const long m = m0 + quad * 4 + r;   // C: col=lane&15, row=quad*4+r
        xp[m * H_DIM + n] = (_Float16)(acc[r] + bias[nt]);
      }
    }
  }
}

// ---------------- recurrent scan kernel ----------------
// h LDS layout (fp16): h[j] at half-index (j>>5)*40 + (j&31)  — 64B data + 16B pad
// per 32-element group -> the 8 broadcast segments of each ds_read_b128 hit the 8
// distinct 4-bank groups (banks = (20c+4q) mod 32, all distinct over c).
__global__ __launch_bounds__(512)
__attribute__((amdgpu_waves_per_eu(2, 2)))   // cap occupancy chase: 256-VGPR budget
void scan_kernel(
    const _Float16* __restrict__ xp,   // (cnt, B, H)
    const float* __restrict__ W_hh,    // (H, H)
    const float* __restrict__ W_fc,    // (C, H)
    const float* __restrict__ b_fc,    // (C)
    float* __restrict__ h_state,       // (B, H) carry between chunks
    float* __restrict__ out,           // (B, C)
    int cnt, int first, int last)
{
  __shared__ __align__(16) _Float16 hbuf[2][320];
  __shared__ float scratch[192];
  const int b   = blockIdx.x;
  const int tid = threadIdx.x;
  const int g   = tid >> 3;   // row group: rows 4g..4g+3
  const int c   = tid & 7;    // col chunk: cols 32c..32c+31

  // W_hh tile -> fp16 packed registers (4 rows x 16 half2 = 64 VGPRs)
  half2v w[4][16];
  const float* wbase = W_hh + (g * 4) * H_DIM + c * 32;
  #pragma unroll
  for (int r = 0; r < 4; ++r)
    #pragma unroll
    for (int i = 0; i < 8; ++i) {
      float4 f = *(const float4*)(wbase + r * H_DIM + i * 4);
      half2v lo, hi;
      lo[0] = (_Float16)f.x; lo[1] = (_Float16)f.y;
      hi[0] = (_Float16)f.z; hi[1] = (_Float16)f.w;
      w[r][2 * i]     = lo;
      w[r][2 * i + 1] = hi;
    }
  // whole-register pins: each half2 is one VGPR; the value becomes asm output,
  // which LLVM will not rematerialize.
  #pragma unroll
  for (int r = 0; r < 4; ++r)
    #pragma unroll
    for (int i = 0; i < 16; ++i)
      asm volatile("" : "+v"(w[r][i]));

  const int row_w = g * 4 + (c & 3);
  const int widx  = (row_w >> 5) * 40 + (row_w & 31);
  if (c < 4)
    hbuf[0][widx] = (_Float16)(first ? 0.f : h_state[b * H_DIM + row_w]);
  __syncthreads();

  // xp prefetch pipeline, 2 steps deep: the loads stay in flight across the
  // LDS-only barriers; vmcnt wait happens at use, ~2 steps (>1000 cyc) later.
  const size_t BH = (size_t)B_DIM * H_DIM;
  const _Float16* xpp = xp + (size_t)b * H_DIM + row_w;
  _Float16 x0 = xpp[0];
  _Float16 x1 = xpp[(cnt > 1 ? 1 : 0) * BH];
  int cur = 0;
  float hnlast = 0.f;

  for (int s = 0; s < cnt; ++s) {
    const int sp = (s + 2 < cnt) ? s + 2 : cnt - 1;
    _Float16 x2 = xpp[(size_t)sp * BH];

    const _Float16* hb = hbuf[cur];
    float a0 = 0.f, a1 = 0.f, a2 = 0.f, a3 = 0.f;
    #pragma unroll
    for (int q = 0; q < 4; ++q) {
      half8v H = *(const half8v*)(hb + c * 40 + q * 8);
      const half2v* hp = (const half2v*)&H;
      #pragma unroll
      for (int i = 0; i < 4; ++i) {
        a0 = fdot2(w[0][q * 4 + i], hp[i], a0);
        a1 = fdot2(w[1][q * 4 + i], hp[i], a1);
        a2 = fdot2(w[2][q * 4 + i], hp[i], a2);
        a3 = fdot2(w[3][q * 4 + i], hp[i], a3);
      }
    }
    // reduce across the 8 column-lanes: butterfly xor {7,3,1}
    a0 = dpp_add<0x141>(a0); a0 = dpp_add<0x1B>(a0); a0 = dpp_add<0xB1>(a0);
    a1 = dpp_add<0x141>(a1); a1 = dpp_add<0x1B>(a1); a1 = dpp_add<0xB1>(a1);
    a2 = dpp_add<0x141>(a2); a2 = dpp_add<0x1B>(a2); a2 = dpp_add<0xB1>(a2);
    a3 = dpp_add<0x141>(a3); a3 = dpp_add<0x1B>(a3); a3 = dpp_add<0xB1>(a3);

    float v01 = (c & 1) ? a1 : a0;
    float v23 = (c & 1) ? a3 : a2;
    float v   = (c & 2) ? v23 : v01;

    float p = v + (float)x0;
    x0 = x1; x1 = x2;
    // tanh(p) = 1 - 2/(e^{2p}+1); saturates correctly at +/-inf
    float e  = __expf(2.f * p);
    float hn = 1.f - __fdividef(2.f, e + 1.f);
    hnlast = hn;
    if (c < 4) hbuf[cur ^ 1][widx] = (_Float16)hn;
    barrier_lds_only();
    cur ^= 1;
  }

  if (c < 4) h_state[b * H_DIM + row_w] = hnlast;

  if (last) {
    const _Float16* hb = hbuf[cur];
    if (tid < 160) {                       // 5 classes x 32 partials
      const int c5 = tid >> 5, i = tid & 31;
      float pp = 0.f;
      #pragma unroll
      for (int jj = 0; jj < 8; ++jj) {
        const int j = i * 8 + jj;
        pp += W_fc[c5 * H_DIM + j] * (float)hb[(j >> 5) * 40 + (j & 31)];
      }
      scratch[tid] = pp;
    }
    __syncthreads();
    if (tid < C_DIM) {
      float l = b_fc[tid];
      for (int i = 0; i < 32; ++i) l += scratch[tid * 32 + i];
      scratch[160 + tid] = l;
    }
    __syncthreads();
    if (tid == 0) {
      float mx = scratch[160];
      for (int i = 1; i < C_DIM; ++i) mx = fmaxf(mx, scratch[160 + i]);
      float se = 0.f;
      for (int i = 0; i < C_DIM; ++i) se += __expf(scratch[160 + i] - mx);
      const float lse = mx + __logf(se);
      for (int i = 0; i < C_DIM; ++i) out[b * C_DIM + i] = scratch[160 + i] - lse;
    }
  }
}

extern "C" void kernel_launch(void* const* d_in, const int* in_sizes, int n_in,
                              void* d_out, int out_size, void* d_ws, size_t ws_size,
                              hipStream_t stream) {
  (void)in_sizes; (void)n_in; (void)out_size;
  const float* x    = (const float*)d_in[0];
  const float* W_ih = (const float*)d_in[1];
  const float* W_hh = (const float*)d_in[2];
  const float* b_ih = (const float*)d_in[3];
  const float* b_hh = (const float*)d_in[4];
  const float* W_fc = (const float*)d_in[5];
  const float* b_fc = (const float*)d_in[6];
  float* out = (float*)d_out;

  char* ws = (char*)d_ws;
  float* h_state = (float*)ws;                              // 64 KB
  _Float16* xp = (_Float16*)(ws + 65536);
  const size_t avail = ws_size > 65536 ? ws_size - 65536 : 0;
  long Tc = (long)(avail / ((size_t)B_DIM * H_DIM * sizeof(_Float16)));
  if (Tc > T_DIM) Tc = T_DIM;
  if (Tc < 1) Tc = 1;

  for (long t0 = 0; t0 < T_DIM; t0 += Tc) {
    const long cnt = (T_DIM - t0 < Tc) ? (T_DIM - t0) : Tc;
    const unsigned xpb = (unsigned)((cnt + TS_PER_BLOCK - 1) / TS_PER_BLOCK);
    xp_kernel<<<dim3(xpb), dim3(256), 0, stream>>>(
        x + t0 * B_DIM * D_DIM, W_ih, b_ih, b_hh, xp, (int)cnt);
    scan_kernel<<<dim3(B_DIM), dim3(512), 0, stream>>>(
        xp, W_hh, W_fc, b_fc, h_state, out,
        (int)cnt, t0 == 0 ? 1 : 0, (t0 + cnt == T_DIM) ? 1 : 0);
  }
}